// Round 14
// baseline (256.902 us; speedup 1.0000x reference)
//
#include <hip/hip_runtime.h>
#include <hip/hip_bf16.h>

#define N_NODES 50000
#define N_EDGES 800000
#define TOT_E (N_EDGES + N_NODES)
#define PS 256                              // nodes per partition
#define NP ((N_NODES + PS - 1) / PS)        // 196 partitions
#define BCAP 6000                           // bucket capacity (avg 4352, sd ~65)
#define NBK 256                             // bucket-pass blocks
#define BCHUNK ((TOT_E + NBK - 1) / NBK)    // 3321 edges/block
// C=128, H=2

typedef unsigned short us8 __attribute__((ext_vector_type(8)));
typedef short s16x8 __attribute__((ext_vector_type(8)));
typedef float f32x4 __attribute__((ext_vector_type(4)));

static __device__ __forceinline__ float lrelu(float v) { return v > 0.0f ? v : 0.2f * v; }

static __device__ __forceinline__ unsigned short f2bf(float f) {
    unsigned int u = __float_as_uint(f);
    unsigned int r = (u + 0x7FFF + ((u >> 16) & 1)) >> 16;  // RNE
    return (unsigned short)r;
}
static __device__ __forceinline__ float bf2f(unsigned short u) {
    return __uint_as_float(((unsigned int)u) << 16);
}

// ---------------- precompute + scratch zeroing ----------------
__global__ __launch_bounds__(256) void wa_kernel(const float* __restrict__ W, const float* __restrict__ as_,
                                                 const float* __restrict__ ad_, float* __restrict__ was,
                                                 float* __restrict__ wad,
                                                 int* __restrict__ gcur, float* __restrict__ stats) {
    int l = blockIdx.x;
    int t = threadIdx.x;
    stats[l * 256 + t] = 0.f;
    if (l == 0 && t < NP) gcur[t] = 0;
    int head = t >> 7, k = t & 127;
    const float* wr = W + (size_t)l * 32768 + (size_t)k * 256 + head * 128;
    const float* ar = as_ + l * 256 + head * 128;
    const float* dr = ad_ + l * 256 + head * 128;
    float s = 0.f, d = 0.f;
    for (int c = 0; c < 128; ++c) {
        float wv = wr[c];
        s += wv * ar[c];
        d += wv * dr[c];
    }
    was[l * 256 + t] = s;
    wad[l * 256 + t] = d;
}

// ---------------- CSR build: single-pass bucket + LDS csr ----------------
__global__ __launch_bounds__(256) void bucket_kernel(const int* __restrict__ ei,
                                                     int* __restrict__ gcur,
                                                     unsigned int* __restrict__ buckets) {
    __shared__ int hist[NP];
    __shared__ int runb[NP];
    __shared__ unsigned int pk[BCHUNK + 7];
    int tid = threadIdx.x;
    for (int t = tid; t < NP; t += 256) hist[t] = 0;
    __syncthreads();
    int lo = blockIdx.x * BCHUNK;
    int hi = lo + BCHUNK < TOT_E ? lo + BCHUNK : TOT_E;
    for (int base = lo; base < lo + BCHUNK; base += 256) {
        int i = base + tid;
        if (i < hi) {
            int s, d;
            if (i < N_EDGES) { s = ei[i]; d = ei[N_EDGES + i]; }
            else { s = d = i - N_EDGES; }
            pk[i - lo] = ((unsigned)d << 16) | (unsigned)s;
            atomicAdd(&hist[d >> 8], 1);
        }
    }
    __syncthreads();
    for (int t = tid; t < NP; t += 256) runb[t] = atomicAdd(&gcur[t], hist[t]);
    __syncthreads();
    for (int base = lo; base < lo + BCHUNK; base += 256) {
        int i = base + tid;
        if (i < hi) {
            unsigned v = pk[i - lo];
            int p = v >> 24;
            int slot = atomicAdd(&runb[p], 1);
            if (slot < BCAP) buckets[(size_t)p * BCAP + slot] = v;
        }
    }
}

__global__ __launch_bounds__(256) void csr_kernel(const int* __restrict__ gcur,
                                                  const unsigned int* __restrict__ buckets,
                                                  int* __restrict__ pbeg, int* __restrict__ pend,
                                                  unsigned short* __restrict__ srcs) {
    __shared__ unsigned int epk[BCAP];      // 24 KB
    __shared__ unsigned short sl[BCAP];     // 12 KB
    __shared__ int deg[256], ps[256], cur[256];
    int p = blockIdx.x, tid = threadIdx.x;
    int len = gcur[p];
    if (len > BCAP) len = BCAP;
    deg[tid] = 0;
    __syncthreads();
    for (int j = tid; j < len; j += 256) {
        unsigned v = buckets[(size_t)p * BCAP + j];
        epk[j] = v;
        atomicAdd(&deg[(v >> 16) & 255], 1);
    }
    __syncthreads();
    int v0 = deg[tid];
    ps[tid] = v0;
    __syncthreads();
#pragma unroll
    for (int o = 1; o < 256; o <<= 1) {
        int u = (tid >= o) ? ps[tid - o] : 0;
        __syncthreads();
        ps[tid] += u;
        __syncthreads();
    }
    int lbeg = ps[tid] - v0;
    cur[tid] = lbeg;
    int n = p * PS + tid;
    if (n < N_NODES) {
        pbeg[n] = p * BCAP + lbeg;
        pend[n] = p * BCAP + lbeg + v0;
    }
    __syncthreads();
    for (int j = tid; j < len; j += 256) {
        unsigned v = epk[j];
        int slot = atomicAdd(&cur[(v >> 16) & 255], 1);
        sl[slot] = (unsigned short)(v & 0xFFFF);
    }
    __syncthreads();
    for (int j = tid; j < len; j += 256) srcs[(size_t)p * BCAP + j] = sl[j];
}

// Mt[l][c][kc] = bf16(0.5*W[l][kc&127][(kc>>7)*128 + c])  (B^T layout, 128 cols x 256 k)
__global__ __launch_bounds__(256) void mt_kernel(const float* __restrict__ W, unsigned short* __restrict__ Mt) {
    int idx = blockIdx.x * 256 + threadIdx.x;  // 65536
    int l = idx >> 15, c = (idx >> 8) & 127, kc = idx & 255;
    int head = kc >> 7, k = kc & 127;
    Mt[idx] = f2bf(0.5f * W[(size_t)l * 32768 + (size_t)k * 256 + head * 128 + c]);
}

// x (fp32) -> xb (bf16) + layer-0 attention logits (32 threads per node, shuffle reduce).
__global__ __launch_bounds__(256) void convert_kernel(const float* __restrict__ x, unsigned short* __restrict__ xb,
                                                      const float* __restrict__ was, const float* __restrict__ wad,
                                                      float2* __restrict__ als, float2* __restrict__ ald) {
    int idx = blockIdx.x * 256 + threadIdx.x;
    int n = idx >> 5;
    int c4 = (idx & 31) * 4;
    float4 v = *(const float4*)(x + (size_t)n * 128 + c4);
    ushort4 o;
    o.x = f2bf(v.x); o.y = f2bf(v.y); o.z = f2bf(v.z); o.w = f2bf(v.w);
    *(ushort4*)(xb + (size_t)n * 128 + c4) = o;
    float4 ws0 = *(const float4*)(was + c4);
    float4 ws1 = *(const float4*)(was + 128 + c4);
    float4 wd0 = *(const float4*)(wad + c4);
    float4 wd1 = *(const float4*)(wad + 128 + c4);
    float s0 = v.x * ws0.x + v.y * ws0.y + v.z * ws0.z + v.w * ws0.w;
    float s1 = v.x * ws1.x + v.y * ws1.y + v.z * ws1.z + v.w * ws1.w;
    float d0 = v.x * wd0.x + v.y * wd0.y + v.z * wd0.z + v.w * wd0.w;
    float d1 = v.x * wd1.x + v.y * wd1.y + v.z * wd1.z + v.w * wd1.w;
#pragma unroll
    for (int o2 = 1; o2 < 32; o2 <<= 1) {
        s0 += __shfl_xor(s0, o2);
        s1 += __shfl_xor(s1, o2);
        d0 += __shfl_xor(d0, o2);
        d1 += __shfl_xor(d1, o2);
    }
    if ((idx & 31) == 0) {
        als[n] = make_float2(s0, s1);
        ald[n] = make_float2(d0, d1);
    }
}

// ---------------- fused per-layer kernel: aggregate 32-node tile into LDS, then MFMA GEMM ----------------
// Phase 1: 16-lane group per node, two 16-node passes; y-tile stored in LDS with chunk XOR swizzle
//          (16B chunk index ^= (row&7)) so the GEMM A-reads are conflict-free.
// Phase 2: z @ M + bias with Mt staged in 32KB k-halves (as before); 4 waves = 2 row x 2 col halves;
//          per-wave LDS transpose epilogue -> bf16 preb + fused BN stats.
__global__ __launch_bounds__(256) void aggemm_kernel(const unsigned short* __restrict__ xb,
                                                     const float2* __restrict__ als, const float2* __restrict__ ald,
                                                     const int* __restrict__ pbeg, const int* __restrict__ pend,
                                                     const unsigned short* __restrict__ srcs,
                                                     const unsigned short* __restrict__ Mt,
                                                     const float* __restrict__ bias_,
                                                     unsigned short* __restrict__ preb,
                                                     float* __restrict__ stats) {
    __shared__ unsigned short ytile[32 * 256];   // 16 KB, swizzled
    __shared__ unsigned short lw[128 * 128];     // 32 KB
    __shared__ float redsum[4][64], redsq[4][64];
    int t = threadIdx.x;
    int n0 = blockIdx.x * 32;

    // ---- phase 1: aggregation ----
    for (int half = 0; half < 2; ++half) {
        int nl = half * 16 + (t >> 4);   // local row 0..31
        int n = n0 + nl;
        int gl = t & 15;
        int cb = gl * 8;                 // logical col base
        int e0 = (gl ^ (nl & 7)) * 8;    // swizzled element offset (head0); head1 = +128
        unsigned short* yp = ytile + nl * 256;
        if (n < N_NODES) {
            int b = pbeg[n], e = pend[n];
            float2 ad = ald[n];
            float a0[8], a1[8];
#pragma unroll
            for (int j = 0; j < 8; ++j) { a0[j] = 0.f; a1[j] = 0.f; }
            float d0 = 0.f, d1 = 0.f;
            int len = e - b;
            int m = len >> 1;
            int b2 = b + m;
            int lenB = len - m;
            for (int i = 0; i < lenB; ++i) {
                bool actA = i < m;
                int iA = actA ? (b + i) : (b2 + i);
                int sA = srcs[iA];
                int sB = srcs[b2 + i];
                float2 asA = als[sA];
                float2 asB = als[sB];
                us8 vA = *(const us8*)(xb + (size_t)sA * 128 + cb);
                us8 vB = *(const us8*)(xb + (size_t)sB * 128 + cb);
                float w0A = actA ? __expf(lrelu(asA.x + ad.x)) : 0.f;
                float w1A = actA ? __expf(lrelu(asA.y + ad.y)) : 0.f;
                float w0B = __expf(lrelu(asB.x + ad.x));
                float w1B = __expf(lrelu(asB.y + ad.y));
                d0 += w0A + w0B;
                d1 += w1A + w1B;
#pragma unroll
                for (int j = 0; j < 8; ++j) {
                    float fA = bf2f(vA[j]);
                    float fB = bf2f(vB[j]);
                    a0[j] += w0A * fA + w0B * fB;
                    a1[j] += w1A * fA + w1B * fB;
                }
            }
            float i0 = 1.0f / d0, i1 = 1.0f / d1;
            us8 o0, o1;
#pragma unroll
            for (int j = 0; j < 8; ++j) {
                o0[j] = f2bf(a0[j] * i0);
                o1[j] = f2bf(a1[j] * i1);
            }
            *(us8*)(yp + e0) = o0;
            *(us8*)(yp + 128 + e0) = o1;
        } else {
            us8 z = (us8){0, 0, 0, 0, 0, 0, 0, 0};
            *(us8*)(yp + e0) = z;
            *(us8*)(yp + 128 + e0) = z;
        }
    }
    __syncthreads();

    // ---- phase 2: GEMM ----
    int w = t >> 6, l = t & 63;
    int lrow = l & 15;
    int lk = l >> 4;
    int rw = (w & 1) * 16;     // tile-row base
    int cw = (w >> 1) * 64;    // out-col base

    f32x4 acc[4];
#pragma unroll
    for (int i = 0; i < 4; ++i) acc[i] = (f32x4){0.f, 0.f, 0.f, 0.f};

    for (int kh = 0; kh < 2; ++kh) {
#pragma unroll
        for (int i = 0; i < 8; ++i) {
            int chunk = t + i * 256;            // 0..2047
            int row = chunk >> 4;               // Mt col 0..127
            int kc8 = chunk & 15;
            uint4 v = *(const uint4*)(Mt + (size_t)row * 256 + kh * 128 + kc8 * 8);
            int b = row * 256 + ((kc8 * 16) ^ ((row & 7) << 4));
            *(uint4*)((char*)lw + b) = v;
        }
        __syncthreads();
        s16x8 a[4];
        int r = rw + lrow;
#pragma unroll
        for (int ka = 0; ka < 4; ++ka) {
            int c = kh * 16 + ka * 4 + lk;      // 16B-chunk index in y row
            a[ka] = *(const s16x8*)(ytile + r * 256 + ((c ^ (r & 7)) * 8));
        }
#pragma unroll
        for (int ct = 0; ct < 4; ++ct) {
            int row = cw + ct * 16 + lrow;
#pragma unroll
            for (int ka = 0; ka < 4; ++ka) {
                int kb = (ka * 64 + lk * 16) ^ ((row & 7) << 4);
                s16x8 bf = *(const s16x8*)((const char*)lw + row * 256 + kb);
                acc[ct] = __builtin_amdgcn_mfma_f32_16x16x32_bf16(a[ka], bf, acc[ct], 0, 0, 0);
            }
        }
        __syncthreads();
    }

    // ---- epilogue: per-wave LDS transpose -> bf16 preb + BN stats ----
    float* fl = (float*)lw;
    int wbase = w * 352;          // 4 rows x 88 words, wave-private
    int lr2 = l >> 4;             // 0..3
    int c4 = (l & 15) * 4;        // 0..60 within wave's 64 cols
    float4 bv = *(const float4*)(bias_ + cw + c4);
    float ssum[4], ssq[4];
#pragma unroll
    for (int j = 0; j < 4; ++j) { ssum[j] = 0.f; ssq[j] = 0.f; }
#pragma unroll
    for (int reg = 0; reg < 4; ++reg) {
#pragma unroll
        for (int ct = 0; ct < 4; ++ct)
            fl[wbase + lk * 88 + ct * 20 + lrow] = acc[ct][reg];
        int ra = wbase + lr2 * 88 + (c4 >> 4) * 20 + (c4 & 15);
        f32x4 v0 = *(const f32x4*)(fl + ra);
        int row = n0 + rw + lr2 * 4 + reg;
        if (row < N_NODES) {
            float vals[4] = {v0[0] + bv.x, v0[1] + bv.y, v0[2] + bv.z, v0[3] + bv.w};
            ushort4 ob;
#pragma unroll
            for (int j = 0; j < 4; ++j) {
                ((unsigned short*)&ob)[j] = f2bf(vals[j]);
                ssum[j] += vals[j];
                ssq[j] += vals[j] * vals[j];
            }
            *(ushort4*)(preb + (size_t)row * 128 + cw + c4) = ob;
        }
    }
#pragma unroll
    for (int j = 0; j < 4; ++j) {
        ssum[j] += __shfl_xor(ssum[j], 16);
        ssum[j] += __shfl_xor(ssum[j], 32);
        ssq[j] += __shfl_xor(ssq[j], 16);
        ssq[j] += __shfl_xor(ssq[j], 32);
    }
    if (l < 16) {
#pragma unroll
        for (int j = 0; j < 4; ++j) {
            redsum[w][c4 + j] = ssum[j];
            redsq[w][c4 + j] = ssq[j];
        }
    }
    __syncthreads();
    float contrib;
    if (t < 64) contrib = redsum[0][t] + redsum[1][t];
    else if (t < 128) contrib = redsum[2][t - 64] + redsum[3][t - 64];
    else if (t < 192) contrib = redsq[0][t - 128] + redsq[1][t - 128];
    else contrib = redsq[2][t - 192] + redsq[3][t - 192];
    atomicAdd(&stats[t], contrib);
}

// BN + ELU + residual from bf16 pre. Residual from fp32 (resf, layer 0) or bf16 (resb, layer 1).
// Layer 0 writes ONLY bf16 xb_out (+ next-layer logits); layer 1 writes only fp32 out.
__global__ __launch_bounds__(256) void final_kernel(const unsigned short* __restrict__ preb,
                                                    const float* __restrict__ resf,
                                                    const unsigned short* __restrict__ resb,
                                                    const float* __restrict__ gamma, const float* __restrict__ beta,
                                                    const float* __restrict__ stats, float* __restrict__ out,
                                                    unsigned short* __restrict__ xb_out,
                                                    const float* __restrict__ was_n, const float* __restrict__ wad_n,
                                                    float2* __restrict__ als_o, float2* __restrict__ ald_o) {
    const float invn = 1.0f / (float)N_NODES;
    int idx = blockIdx.x * 256 + threadIdx.x;
    int n = idx >> 4;
    int c8 = (idx & 15) * 8;
    us8 pv = *(const us8*)(preb + (size_t)n * 128 + c8);
    float rs[8];
    if (resf) {
        float4 r0 = *(const float4*)(resf + (size_t)n * 128 + c8);
        float4 r1 = *(const float4*)(resf + (size_t)n * 128 + c8 + 4);
        rs[0] = r0.x; rs[1] = r0.y; rs[2] = r0.z; rs[3] = r0.w;
        rs[4] = r1.x; rs[5] = r1.y; rs[6] = r1.z; rs[7] = r1.w;
    } else {
        us8 rv = *(const us8*)(resb + (size_t)n * 128 + c8);
#pragma unroll
        for (int j = 0; j < 8; ++j) rs[j] = bf2f(rv[j]);
    }
    float4 sm0 = *(const float4*)(stats + c8);
    float4 sm1 = *(const float4*)(stats + c8 + 4);
    float4 sq0 = *(const float4*)(stats + 128 + c8);
    float4 sq1 = *(const float4*)(stats + 128 + c8 + 4);
    float4 g0 = *(const float4*)(gamma + c8);
    float4 g1 = *(const float4*)(gamma + c8 + 4);
    float4 bt0 = *(const float4*)(beta + c8);
    float4 bt1 = *(const float4*)(beta + c8 + 4);
    float sm[8] = {sm0.x, sm0.y, sm0.z, sm0.w, sm1.x, sm1.y, sm1.z, sm1.w};
    float sq[8] = {sq0.x, sq0.y, sq0.z, sq0.w, sq1.x, sq1.y, sq1.z, sq1.w};
    float gg[8] = {g0.x, g0.y, g0.z, g0.w, g1.x, g1.y, g1.z, g1.w};
    float bb[8] = {bt0.x, bt0.y, bt0.z, bt0.w, bt1.x, bt1.y, bt1.z, bt1.w};
    float vals[8];
#pragma unroll
    for (int j = 0; j < 8; ++j) {
        float mean = sm[j] * invn;
        float var = sq[j] * invn - mean * mean;
        float is = rsqrtf(var + 1e-5f) * gg[j];
        float val = (bf2f(pv[j]) - mean) * is + bb[j];
        val = val > 0.f ? val : (__expf(val) - 1.0f);
        vals[j] = val + rs[j];
    }
    if (out) {
        float* op = out + (size_t)n * 128 + c8;
        *(float4*)op = make_float4(vals[0], vals[1], vals[2], vals[3]);
        *(float4*)(op + 4) = make_float4(vals[4], vals[5], vals[6], vals[7]);
    }
    if (xb_out) {
        us8 ob;
#pragma unroll
        for (int j = 0; j < 8; ++j) ob[j] = f2bf(vals[j]);
        *(us8*)(xb_out + (size_t)n * 128 + c8) = ob;
        // next-layer attention logits
        float s0 = 0.f, s1 = 0.f, d0 = 0.f, d1 = 0.f;
#pragma unroll
        for (int j = 0; j < 8; ++j) {
            int c = c8 + j;
            s0 += vals[j] * was_n[c];
            s1 += vals[j] * was_n[128 + c];
            d0 += vals[j] * wad_n[c];
            d1 += vals[j] * wad_n[128 + c];
        }
#pragma unroll
        for (int o = 1; o < 16; o <<= 1) {
            s0 += __shfl_xor(s0, o);
            s1 += __shfl_xor(s1, o);
            d0 += __shfl_xor(d0, o);
            d1 += __shfl_xor(d1, o);
        }
        if ((idx & 15) == 0) {
            als_o[n] = make_float2(s0, s1);
            ald_o[n] = make_float2(d0, d1);
        }
    }
}

extern "C" void kernel_launch(void* const* d_in, const int* in_sizes, int n_in,
                              void* d_out, int out_size, void* d_ws, size_t ws_size,
                              hipStream_t stream) {
    const float* x0   = (const float*)d_in[0];
    const int* ei     = (const int*)d_in[1];
    const float* W    = (const float*)d_in[2];
    const float* asrc = (const float*)d_in[3];
    const float* adst = (const float*)d_in[4];
    const float* bias = (const float*)d_in[5];
    const float* gam  = (const float*)d_in[6];
    const float* bet  = (const float*)d_in[7];
    float* out = (float*)d_out;

    char* ws = (char*)d_ws;
    size_t off = 0;
    auto alloc = [&](size_t bytes) -> void* {
        void* p = ws + off;
        off += (bytes + 255) & ~(size_t)255;
        return p;
    };
    int* gcur   = (int*)alloc((size_t)NP * 4);
    unsigned int* buckets = (unsigned int*)alloc((size_t)NP * BCAP * 4);
    unsigned short* srcs  = (unsigned short*)alloc((size_t)NP * BCAP * 2);
    int* pbeg   = (int*)alloc((size_t)N_NODES * 4);
    int* pend   = (int*)alloc((size_t)N_NODES * 4);
    unsigned short* xb = (unsigned short*)alloc((size_t)N_NODES * 128 * 2);   // bf16 layer input / L1 residual
    unsigned short* preb = (unsigned short*)alloc((size_t)N_NODES * 128 * 2); // bf16 pre-BN
    unsigned short* Mt = (unsigned short*)alloc((size_t)2 * 128 * 256 * 2);   // bf16 M^T per layer
    float* was  = (float*)alloc(512 * 4);
    float* wad  = (float*)alloc(512 * 4);
    float* als  = (float*)alloc((size_t)N_NODES * 2 * 4);
    float* ald  = (float*)alloc((size_t)N_NODES * 2 * 4);
    float* stats = (float*)alloc(512 * 4);

    wa_kernel<<<2, 256, 0, stream>>>(W, asrc, adst, was, wad, gcur, stats);
    bucket_kernel<<<NBK, 256, 0, stream>>>(ei, gcur, buckets);
    csr_kernel<<<NP, 256, 0, stream>>>(gcur, buckets, pbeg, pend, srcs);
    mt_kernel<<<256, 256, 0, stream>>>(W, Mt);
    convert_kernel<<<(N_NODES * 32) / 256, 256, 0, stream>>>(x0, xb, was, wad, (float2*)als, (float2*)ald);

    for (int l = 0; l < 2; ++l) {
        aggemm_kernel<<<(N_NODES + 31) / 32, 256, 0, stream>>>(
            xb, (const float2*)als, (const float2*)ald, pbeg, pend, srcs,
            Mt + (size_t)l * 32768, bias + l * 128, preb, stats + l * 256);
        final_kernel<<<(N_NODES * 16) / 256, 256, 0, stream>>>(
            preb,
            l == 0 ? x0 : (const float*)nullptr,
            l == 0 ? (const unsigned short*)nullptr : xb,
            gam + l * 128, bet + l * 128, stats + l * 256,
            l == 0 ? (float*)nullptr : out,
            l == 0 ? xb : (unsigned short*)nullptr,
            was + 256, wad + 256,
            (float2*)als, (float2*)ald);
    }
}

// Round 15
// 200.716 us; speedup vs baseline: 1.2799x; 1.2799x over previous
//
#include <hip/hip_runtime.h>
#include <hip/hip_bf16.h>

#define N_NODES 50000
#define N_EDGES 800000
#define TOT_E (N_EDGES + N_NODES)
#define PS 256                              // nodes per partition
#define NP ((N_NODES + PS - 1) / PS)        // 196 partitions
#define BCAP 6000                           // bucket capacity (avg 4352, sd ~65)
#define NBK 256                             // bucket-pass blocks
#define BCHUNK ((TOT_E + NBK - 1) / NBK)    // 3321 edges/block
// C=128, H=2

typedef unsigned short us8 __attribute__((ext_vector_type(8)));
typedef short s16x8 __attribute__((ext_vector_type(8)));
typedef float f32x4 __attribute__((ext_vector_type(4)));

static __device__ __forceinline__ float lrelu(float v) { return v > 0.0f ? v : 0.2f * v; }

static __device__ __forceinline__ unsigned short f2bf(float f) {
    unsigned int u = __float_as_uint(f);
    unsigned int r = (u + 0x7FFF + ((u >> 16) & 1)) >> 16;  // RNE
    return (unsigned short)r;
}
static __device__ __forceinline__ float bf2f(unsigned short u) {
    return __uint_as_float(((unsigned int)u) << 16);
}

// ---------------- precompute + scratch zeroing ----------------
// wa_s[l][head][k] = sum_c W[l][k][head*128+c]*as[l][head][c]; same for wa_d. blockIdx = l.
// Also zeroes gcur (block 0) and stats (block l zeroes its 256-float half) — replaces memsets.
__global__ __launch_bounds__(256) void wa_kernel(const float* __restrict__ W, const float* __restrict__ as_,
                                                 const float* __restrict__ ad_, float* __restrict__ was,
                                                 float* __restrict__ wad,
                                                 int* __restrict__ gcur, float* __restrict__ stats) {
    int l = blockIdx.x;
    int t = threadIdx.x;
    stats[l * 256 + t] = 0.f;
    if (l == 0 && t < NP) gcur[t] = 0;
    int head = t >> 7, k = t & 127;
    const float* wr = W + (size_t)l * 32768 + (size_t)k * 256 + head * 128;
    const float* ar = as_ + l * 256 + head * 128;
    const float* dr = ad_ + l * 256 + head * 128;
    float s = 0.f, d = 0.f;
    for (int c = 0; c < 128; ++c) {
        float wv = wr[c];
        s += wv * ar[c];
        d += wv * dr[c];
    }
    was[l * 256 + t] = s;
    wad[l * 256 + t] = d;
}

// ---------------- CSR build: single-pass bucket + LDS csr ----------------
__global__ __launch_bounds__(256) void bucket_kernel(const int* __restrict__ ei,
                                                     int* __restrict__ gcur,
                                                     unsigned int* __restrict__ buckets) {
    __shared__ int hist[NP];
    __shared__ int runb[NP];
    __shared__ unsigned int pk[BCHUNK + 7];
    int tid = threadIdx.x;
    for (int t = tid; t < NP; t += 256) hist[t] = 0;
    __syncthreads();
    int lo = blockIdx.x * BCHUNK;
    int hi = lo + BCHUNK < TOT_E ? lo + BCHUNK : TOT_E;
    for (int base = lo; base < lo + BCHUNK; base += 256) {
        int i = base + tid;
        if (i < hi) {
            int s, d;
            if (i < N_EDGES) { s = ei[i]; d = ei[N_EDGES + i]; }
            else { s = d = i - N_EDGES; }
            pk[i - lo] = ((unsigned)d << 16) | (unsigned)s;
            atomicAdd(&hist[d >> 8], 1);
        }
    }
    __syncthreads();
    for (int t = tid; t < NP; t += 256) runb[t] = atomicAdd(&gcur[t], hist[t]);
    __syncthreads();
    for (int base = lo; base < lo + BCHUNK; base += 256) {
        int i = base + tid;
        if (i < hi) {
            unsigned v = pk[i - lo];
            int p = v >> 24;
            int slot = atomicAdd(&runb[p], 1);
            if (slot < BCAP) buckets[(size_t)p * BCAP + slot] = v;
        }
    }
}

__global__ __launch_bounds__(256) void csr_kernel(const int* __restrict__ gcur,
                                                  const unsigned int* __restrict__ buckets,
                                                  int* __restrict__ pbeg, int* __restrict__ pend,
                                                  unsigned short* __restrict__ srcs) {
    __shared__ unsigned int epk[BCAP];      // 24 KB
    __shared__ unsigned short sl[BCAP];     // 12 KB
    __shared__ int deg[256], ps[256], cur[256];
    int p = blockIdx.x, tid = threadIdx.x;
    int len = gcur[p];
    if (len > BCAP) len = BCAP;
    deg[tid] = 0;
    __syncthreads();
    for (int j = tid; j < len; j += 256) {
        unsigned v = buckets[(size_t)p * BCAP + j];
        epk[j] = v;
        atomicAdd(&deg[(v >> 16) & 255], 1);
    }
    __syncthreads();
    int v0 = deg[tid];
    ps[tid] = v0;
    __syncthreads();
#pragma unroll
    for (int o = 1; o < 256; o <<= 1) {
        int u = (tid >= o) ? ps[tid - o] : 0;
        __syncthreads();
        ps[tid] += u;
        __syncthreads();
    }
    int lbeg = ps[tid] - v0;
    cur[tid] = lbeg;
    int n = p * PS + tid;
    if (n < N_NODES) {
        pbeg[n] = p * BCAP + lbeg;
        pend[n] = p * BCAP + lbeg + v0;
    }
    __syncthreads();
    for (int j = tid; j < len; j += 256) {
        unsigned v = epk[j];
        int slot = atomicAdd(&cur[(v >> 16) & 255], 1);
        sl[slot] = (unsigned short)(v & 0xFFFF);
    }
    __syncthreads();
    for (int j = tid; j < len; j += 256) srcs[(size_t)p * BCAP + j] = sl[j];
}

// Mt[l][c][kc] = bf16(0.5*W[l][kc&127][(kc>>7)*128 + c])  (B^T layout, 128 cols x 256 k)
__global__ __launch_bounds__(256) void mt_kernel(const float* __restrict__ W, unsigned short* __restrict__ Mt) {
    int idx = blockIdx.x * 256 + threadIdx.x;  // 65536
    int l = idx >> 15, c = (idx >> 8) & 127, kc = idx & 255;
    int head = kc >> 7, k = kc & 127;
    Mt[idx] = f2bf(0.5f * W[(size_t)l * 32768 + (size_t)k * 256 + head * 128 + c]);
}

// x (fp32) -> xb (bf16) + layer-0 attention logits (32 threads per node, shuffle reduce).
__global__ __launch_bounds__(256) void convert_kernel(const float* __restrict__ x, unsigned short* __restrict__ xb,
                                                      const float* __restrict__ was, const float* __restrict__ wad,
                                                      float2* __restrict__ als, float2* __restrict__ ald) {
    int idx = blockIdx.x * 256 + threadIdx.x;
    int n = idx >> 5;
    int c4 = (idx & 31) * 4;
    float4 v = *(const float4*)(x + (size_t)n * 128 + c4);
    ushort4 o;
    o.x = f2bf(v.x); o.y = f2bf(v.y); o.z = f2bf(v.z); o.w = f2bf(v.w);
    *(ushort4*)(xb + (size_t)n * 128 + c4) = o;
    float4 ws0 = *(const float4*)(was + c4);
    float4 ws1 = *(const float4*)(was + 128 + c4);
    float4 wd0 = *(const float4*)(wad + c4);
    float4 wd1 = *(const float4*)(wad + 128 + c4);
    float s0 = v.x * ws0.x + v.y * ws0.y + v.z * ws0.z + v.w * ws0.w;
    float s1 = v.x * ws1.x + v.y * ws1.y + v.z * ws1.z + v.w * ws1.w;
    float d0 = v.x * wd0.x + v.y * wd0.y + v.z * wd0.z + v.w * wd0.w;
    float d1 = v.x * wd1.x + v.y * wd1.y + v.z * wd1.z + v.w * wd1.w;
#pragma unroll
    for (int o2 = 1; o2 < 32; o2 <<= 1) {
        s0 += __shfl_xor(s0, o2);
        s1 += __shfl_xor(s1, o2);
        d0 += __shfl_xor(d0, o2);
        d1 += __shfl_xor(d1, o2);
    }
    if ((idx & 31) == 0) {
        als[n] = make_float2(s0, s1);
        ald[n] = make_float2(d0, d1);
    }
}

// ---------------- per-layer kernels ----------------
// 16-lane group per node (4 consecutive nodes/wave); lane covers 8 bf16 cols.
// FOUR independent edge streams per group (ILP x4): 16 row-gathers in flight per wave.
__global__ __launch_bounds__(256) void agg_kernel(const unsigned short* __restrict__ xb,
                                                  const float2* __restrict__ als, const float2* __restrict__ ald,
                                                  const int* __restrict__ pbeg, const int* __restrict__ pend,
                                                  const unsigned short* __restrict__ srcs,
                                                  unsigned short* __restrict__ y) {
    int tid = blockIdx.x * 256 + threadIdx.x;
    int n = tid >> 4;
    int gl = tid & 15;
    if (n >= N_NODES) return;
    int b = pbeg[n], e = pend[n];
    float2 ad = ald[n];
    int cb = gl * 8;   // col base

    float a0[8], a1[8];
#pragma unroll
    for (int j = 0; j < 8; ++j) { a0[j] = 0.f; a1[j] = 0.f; }
    float d0 = 0.f, d1 = 0.f;

    int len = e - b;
    int L = (len + 3) >> 2;   // iterations; stream k covers [b+k*L, ...)
    for (int i = 0; i < L; ++i) {
        int o0i = i;
        int o1i = L + i;
        int o2i = 2 * L + i;
        int o3i = 3 * L + i;
        bool c0 = o0i < len, c1 = o1i < len, c2 = o2i < len, c3 = o3i < len;
        int i0 = b + (c0 ? o0i : 0);
        int i1 = b + (c1 ? o1i : 0);
        int i2 = b + (c2 ? o2i : 0);
        int i3 = b + (c3 ? o3i : 0);
        int s0 = srcs[i0], s1 = srcs[i1], s2 = srcs[i2], s3 = srcs[i3];
        float2 A0 = als[s0], A1 = als[s1], A2 = als[s2], A3 = als[s3];
        us8 v0 = *(const us8*)(xb + (size_t)s0 * 128 + cb);
        us8 v1 = *(const us8*)(xb + (size_t)s1 * 128 + cb);
        us8 v2 = *(const us8*)(xb + (size_t)s2 * 128 + cb);
        us8 v3 = *(const us8*)(xb + (size_t)s3 * 128 + cb);
        float w00 = c0 ? __expf(lrelu(A0.x + ad.x)) : 0.f;
        float w10 = c0 ? __expf(lrelu(A0.y + ad.y)) : 0.f;
        float w01 = c1 ? __expf(lrelu(A1.x + ad.x)) : 0.f;
        float w11 = c1 ? __expf(lrelu(A1.y + ad.y)) : 0.f;
        float w02 = c2 ? __expf(lrelu(A2.x + ad.x)) : 0.f;
        float w12 = c2 ? __expf(lrelu(A2.y + ad.y)) : 0.f;
        float w03 = c3 ? __expf(lrelu(A3.x + ad.x)) : 0.f;
        float w13 = c3 ? __expf(lrelu(A3.y + ad.y)) : 0.f;
        d0 += (w00 + w01) + (w02 + w03);
        d1 += (w10 + w11) + (w12 + w13);
#pragma unroll
        for (int j = 0; j < 8; ++j) {
            float f0 = bf2f(v0[j]);
            float f1 = bf2f(v1[j]);
            float f2 = bf2f(v2[j]);
            float f3 = bf2f(v3[j]);
            a0[j] += (w00 * f0 + w01 * f1) + (w02 * f2 + w03 * f3);
            a1[j] += (w10 * f0 + w11 * f1) + (w12 * f2 + w13 * f3);
        }
    }

    float i0v = 1.0f / d0, i1v = 1.0f / d1;
    us8 o0, o1;
#pragma unroll
    for (int j = 0; j < 8; ++j) {
        o0[j] = f2bf(a0[j] * i0v);
        o1[j] = f2bf(a1[j] * i1v);
    }
    unsigned short* yp = y + (size_t)n * 256 + cb;
    *(us8*)yp = o0;
    *(us8*)(yp + 128) = o1;
}

// pre = z @ M + bias : (N,256)bf16 @ (256,128) -> bf16 (N,128) + fused BN stats.
__global__ __launch_bounds__(256) void gemm2_kernel(const unsigned short* __restrict__ zb,
                                                    const unsigned short* __restrict__ Mt,
                                                    const float* __restrict__ bias_,
                                                    unsigned short* __restrict__ preb,
                                                    float* __restrict__ stats) {
    __shared__ unsigned short lw[128 * 128];  // 32KB
    __shared__ float redsum[4][128];
    __shared__ float redsq[4][128];
    int t = threadIdx.x;
    int w = t >> 6, l = t & 63;
    int r0 = blockIdx.x * 64 + w * 16;
    int lrow = l & 15;
    int lk = l >> 4;

    int arow = r0 + lrow;
    if (arow >= N_NODES) arow = N_NODES - 1;

    f32x4 acc[8];
#pragma unroll
    for (int i = 0; i < 8; ++i) acc[i] = (f32x4){0.f, 0.f, 0.f, 0.f};

    for (int kh = 0; kh < 2; ++kh) {
#pragma unroll
        for (int i = 0; i < 8; ++i) {
            int chunk = t + i * 256;            // 0..2047
            int row = chunk >> 4;               // col 0..127
            int kc8 = chunk & 15;
            uint4 v = *(const uint4*)(Mt + (size_t)row * 256 + kh * 128 + kc8 * 8);
            int b = row * 256 + ((kc8 * 16) ^ ((row & 7) << 4));
            *(uint4*)((char*)lw + b) = v;
        }
        __syncthreads();
        s16x8 a[4];
#pragma unroll
        for (int ka = 0; ka < 4; ++ka)
            a[ka] = *(const s16x8*)(zb + (size_t)arow * 256 + kh * 128 + ka * 32 + lk * 8);
#pragma unroll
        for (int ct = 0; ct < 8; ++ct) {
            int row = ct * 16 + lrow;
#pragma unroll
            for (int ka = 0; ka < 4; ++ka) {
                int kb = (ka * 64 + lk * 16) ^ ((row & 7) << 4);
                s16x8 bf = *(const s16x8*)((const char*)lw + row * 256 + kb);
                acc[ct] = __builtin_amdgcn_mfma_f32_16x16x32_bf16(a[ka], bf, acc[ct], 0, 0, 0);
            }
        }
        __syncthreads();   // all waves done reading lw before epilogue reuses it
    }

    // epilogue: per-wave LDS transpose -> bf16 stores + stats accumulation (no syncs)
    float* fl = (float*)lw;
    int wbase = w * 704;  // 4 rows x 176 words per wave (private region)
    int lr2 = l >> 4;
    int cb2 = (l & 15) * 8;
    float4 b0 = *(const float4*)(bias_ + cb2);
    float4 b1 = *(const float4*)(bias_ + cb2 + 4);
    float ssum[8], ssq[8];
#pragma unroll
    for (int j = 0; j < 8; ++j) { ssum[j] = 0.f; ssq[j] = 0.f; }
#pragma unroll
    for (int reg = 0; reg < 4; ++reg) {
#pragma unroll
        for (int ct = 0; ct < 8; ++ct)
            fl[wbase + lk * 176 + ct * 20 + lrow] = acc[ct][reg];
        int ra = wbase + lr2 * 176 + (cb2 >> 4) * 20 + (cb2 & 15);
        f32x4 v0 = *(const f32x4*)(fl + ra);
        f32x4 v1 = *(const f32x4*)(fl + ra + 4);
        int row = r0 + lr2 * 4 + reg;
        if (row < N_NODES) {
            float vals[8] = {v0[0] + b0.x, v0[1] + b0.y, v0[2] + b0.z, v0[3] + b0.w,
                             v1[0] + b1.x, v1[1] + b1.y, v1[2] + b1.z, v1[3] + b1.w};
            us8 ob;
#pragma unroll
            for (int j = 0; j < 8; ++j) {
                ob[j] = f2bf(vals[j]);
                ssum[j] += vals[j];
                ssq[j] += vals[j] * vals[j];
            }
            *(us8*)(preb + (size_t)row * 128 + cb2) = ob;
        }
    }
    // stats: reduce the 4 lanes sharing cb2 (xor 16, 32), stash per wave, reduce waves, atomics
#pragma unroll
    for (int j = 0; j < 8; ++j) {
        ssum[j] += __shfl_xor(ssum[j], 16);
        ssum[j] += __shfl_xor(ssum[j], 32);
        ssq[j] += __shfl_xor(ssq[j], 16);
        ssq[j] += __shfl_xor(ssq[j], 32);
    }
    if (l < 16) {
#pragma unroll
        for (int j = 0; j < 8; ++j) {
            redsum[w][cb2 + j] = ssum[j];
            redsq[w][cb2 + j] = ssq[j];
        }
    }
    __syncthreads();
    if (t < 128) {
        atomicAdd(&stats[t], redsum[0][t] + redsum[1][t] + redsum[2][t] + redsum[3][t]);
    } else if (t < 256) {
        int c = t - 128;
        atomicAdd(&stats[128 + c], redsq[0][c] + redsq[1][c] + redsq[2][c] + redsq[3][c]);
    }
}

// BN + ELU + residual from bf16 pre. Residual from fp32 (resf, layer 0) or bf16 (resb, layer 1).
// Layer 0 writes ONLY bf16 xb_out (+ next-layer logits); layer 1 writes only fp32 out.
__global__ __launch_bounds__(256) void final_kernel(const unsigned short* __restrict__ preb,
                                                    const float* __restrict__ resf,
                                                    const unsigned short* __restrict__ resb,
                                                    const float* __restrict__ gamma, const float* __restrict__ beta,
                                                    const float* __restrict__ stats, float* __restrict__ out,
                                                    unsigned short* __restrict__ xb_out,
                                                    const float* __restrict__ was_n, const float* __restrict__ wad_n,
                                                    float2* __restrict__ als_o, float2* __restrict__ ald_o) {
    const float invn = 1.0f / (float)N_NODES;
    int idx = blockIdx.x * 256 + threadIdx.x;
    int n = idx >> 4;
    int c8 = (idx & 15) * 8;
    us8 pv = *(const us8*)(preb + (size_t)n * 128 + c8);
    float rs[8];
    if (resf) {
        float4 r0 = *(const float4*)(resf + (size_t)n * 128 + c8);
        float4 r1 = *(const float4*)(resf + (size_t)n * 128 + c8 + 4);
        rs[0] = r0.x; rs[1] = r0.y; rs[2] = r0.z; rs[3] = r0.w;
        rs[4] = r1.x; rs[5] = r1.y; rs[6] = r1.z; rs[7] = r1.w;
    } else {
        us8 rv = *(const us8*)(resb + (size_t)n * 128 + c8);
#pragma unroll
        for (int j = 0; j < 8; ++j) rs[j] = bf2f(rv[j]);
    }
    float4 sm0 = *(const float4*)(stats + c8);
    float4 sm1 = *(const float4*)(stats + c8 + 4);
    float4 sq0 = *(const float4*)(stats + 128 + c8);
    float4 sq1 = *(const float4*)(stats + 128 + c8 + 4);
    float4 g0 = *(const float4*)(gamma + c8);
    float4 g1 = *(const float4*)(gamma + c8 + 4);
    float4 bt0 = *(const float4*)(beta + c8);
    float4 bt1 = *(const float4*)(beta + c8 + 4);
    float sm[8] = {sm0.x, sm0.y, sm0.z, sm0.w, sm1.x, sm1.y, sm1.z, sm1.w};
    float sq[8] = {sq0.x, sq0.y, sq0.z, sq0.w, sq1.x, sq1.y, sq1.z, sq1.w};
    float gg[8] = {g0.x, g0.y, g0.z, g0.w, g1.x, g1.y, g1.z, g1.w};
    float bb[8] = {bt0.x, bt0.y, bt0.z, bt0.w, bt1.x, bt1.y, bt1.z, bt1.w};
    float vals[8];
#pragma unroll
    for (int j = 0; j < 8; ++j) {
        float mean = sm[j] * invn;
        float var = sq[j] * invn - mean * mean;
        float is = rsqrtf(var + 1e-5f) * gg[j];
        float val = (bf2f(pv[j]) - mean) * is + bb[j];
        val = val > 0.f ? val : (__expf(val) - 1.0f);
        vals[j] = val + rs[j];
    }
    if (out) {
        float* op = out + (size_t)n * 128 + c8;
        *(float4*)op = make_float4(vals[0], vals[1], vals[2], vals[3]);
        *(float4*)(op + 4) = make_float4(vals[4], vals[5], vals[6], vals[7]);
    }
    if (xb_out) {
        us8 ob;
#pragma unroll
        for (int j = 0; j < 8; ++j) ob[j] = f2bf(vals[j]);
        *(us8*)(xb_out + (size_t)n * 128 + c8) = ob;
        // next-layer attention logits
        float s0 = 0.f, s1 = 0.f, d0 = 0.f, d1 = 0.f;
#pragma unroll
        for (int j = 0; j < 8; ++j) {
            int c = c8 + j;
            s0 += vals[j] * was_n[c];
            s1 += vals[j] * was_n[128 + c];
            d0 += vals[j] * wad_n[c];
            d1 += vals[j] * wad_n[128 + c];
        }
#pragma unroll
        for (int o = 1; o < 16; o <<= 1) {
            s0 += __shfl_xor(s0, o);
            s1 += __shfl_xor(s1, o);
            d0 += __shfl_xor(d0, o);
            d1 += __shfl_xor(d1, o);
        }
        if ((idx & 15) == 0) {
            als_o[n] = make_float2(s0, s1);
            ald_o[n] = make_float2(d0, d1);
        }
    }
}

extern "C" void kernel_launch(void* const* d_in, const int* in_sizes, int n_in,
                              void* d_out, int out_size, void* d_ws, size_t ws_size,
                              hipStream_t stream) {
    const float* x0   = (const float*)d_in[0];
    const int* ei     = (const int*)d_in[1];
    const float* W    = (const float*)d_in[2];
    const float* asrc = (const float*)d_in[3];
    const float* adst = (const float*)d_in[4];
    const float* bias = (const float*)d_in[5];
    const float* gam  = (const float*)d_in[6];
    const float* bet  = (const float*)d_in[7];
    float* out = (float*)d_out;

    char* ws = (char*)d_ws;
    size_t off = 0;
    auto alloc = [&](size_t bytes) -> void* {
        void* p = ws + off;
        off += (bytes + 255) & ~(size_t)255;
        return p;
    };
    int* gcur   = (int*)alloc((size_t)NP * 4);
    unsigned int* buckets = (unsigned int*)alloc((size_t)NP * BCAP * 4);
    unsigned short* srcs  = (unsigned short*)alloc((size_t)NP * BCAP * 2);
    int* pbeg   = (int*)alloc((size_t)N_NODES * 4);
    int* pend   = (int*)alloc((size_t)N_NODES * 4);
    unsigned short* xb = (unsigned short*)alloc((size_t)N_NODES * 128 * 2);   // bf16 layer input / L1 residual
    unsigned short* y  = (unsigned short*)alloc((size_t)N_NODES * 256 * 2);   // bf16 z = [y_h0|y_h1]
    unsigned short* preb = (unsigned short*)alloc((size_t)N_NODES * 128 * 2); // bf16 pre-BN
    unsigned short* Mt = (unsigned short*)alloc((size_t)2 * 128 * 256 * 2);   // bf16 M^T per layer
    float* was  = (float*)alloc(512 * 4);
    float* wad  = (float*)alloc(512 * 4);
    float* als  = (float*)alloc((size_t)N_NODES * 2 * 4);
    float* ald  = (float*)alloc((size_t)N_NODES * 2 * 4);
    float* stats = (float*)alloc(512 * 4);

    wa_kernel<<<2, 256, 0, stream>>>(W, asrc, adst, was, wad, gcur, stats);
    bucket_kernel<<<NBK, 256, 0, stream>>>(ei, gcur, buckets);
    csr_kernel<<<NP, 256, 0, stream>>>(gcur, buckets, pbeg, pend, srcs);
    mt_kernel<<<256, 256, 0, stream>>>(W, Mt);
    convert_kernel<<<(N_NODES * 32) / 256, 256, 0, stream>>>(x0, xb, was, wad, (float2*)als, (float2*)ald);

    for (int l = 0; l < 2; ++l) {
        agg_kernel<<<(N_NODES * 16 + 255) / 256, 256, 0, stream>>>(
            xb, (const float2*)als, (const float2*)ald, pbeg, pend, srcs, y);
        gemm2_kernel<<<(N_NODES + 63) / 64, 256, 0, stream>>>(
            y, Mt + (size_t)l * 32768, bias + l * 128, preb, stats + l * 256);
        final_kernel<<<(N_NODES * 16) / 256, 256, 0, stream>>>(
            preb,
            l == 0 ? x0 : (const float*)nullptr,
            l == 0 ? (const unsigned short*)nullptr : xb,
            gam + l * 128, bet + l * 128, stats + l * 256,
            l == 0 ? (float*)nullptr : out,
            l == 0 ? xb : (unsigned short*)nullptr,
            was + 256, wad + 256,
            (float2*)als, (float2*)ald);
    }
}

// Round 16
// 199.778 us; speedup vs baseline: 1.2859x; 1.0047x over previous
//
#include <hip/hip_runtime.h>
#include <hip/hip_bf16.h>

#define N_NODES 50000
#define N_EDGES 800000
#define TOT_E (N_EDGES + N_NODES)
#define PS 256                              // nodes per partition
#define NP ((N_NODES + PS - 1) / PS)        // 196 partitions
#define BCAP 6000                           // bucket capacity (avg 4352, sd ~65)
#define NBK 256                             // bucket-pass blocks
#define BCHUNK ((TOT_E + NBK - 1) / NBK)    // 3321 edges/block
// C=128, H=2

typedef unsigned short us8 __attribute__((ext_vector_type(8)));
typedef short s16x8 __attribute__((ext_vector_type(8)));
typedef float f32x4 __attribute__((ext_vector_type(4)));

static __device__ __forceinline__ float lrelu(float v) { return v > 0.0f ? v : 0.2f * v; }

static __device__ __forceinline__ unsigned short f2bf(float f) {
    unsigned int u = __float_as_uint(f);
    unsigned int r = (u + 0x7FFF + ((u >> 16) & 1)) >> 16;  // RNE
    return (unsigned short)r;
}
static __device__ __forceinline__ float bf2f(unsigned short u) {
    return __uint_as_float(((unsigned int)u) << 16);
}

// ---------------- precompute + scratch zeroing ----------------
__global__ __launch_bounds__(256) void wa_kernel(const float* __restrict__ W, const float* __restrict__ as_,
                                                 const float* __restrict__ ad_, float* __restrict__ was,
                                                 float* __restrict__ wad,
                                                 int* __restrict__ gcur, float* __restrict__ stats) {
    int l = blockIdx.x;
    int t = threadIdx.x;
    stats[l * 256 + t] = 0.f;
    if (l == 0 && t < NP) gcur[t] = 0;
    int head = t >> 7, k = t & 127;
    const float* wr = W + (size_t)l * 32768 + (size_t)k * 256 + head * 128;
    const float* ar = as_ + l * 256 + head * 128;
    const float* dr = ad_ + l * 256 + head * 128;
    float s = 0.f, d = 0.f;
    for (int c = 0; c < 128; ++c) {
        float wv = wr[c];
        s += wv * ar[c];
        d += wv * dr[c];
    }
    was[l * 256 + t] = s;
    wad[l * 256 + t] = d;
}

// ---------------- CSR build: single-pass bucket + LDS csr ----------------
__global__ __launch_bounds__(256) void bucket_kernel(const int* __restrict__ ei,
                                                     int* __restrict__ gcur,
                                                     unsigned int* __restrict__ buckets) {
    __shared__ int hist[NP];
    __shared__ int runb[NP];
    __shared__ unsigned int pk[BCHUNK + 7];
    int tid = threadIdx.x;
    for (int t = tid; t < NP; t += 256) hist[t] = 0;
    __syncthreads();
    int lo = blockIdx.x * BCHUNK;
    int hi = lo + BCHUNK < TOT_E ? lo + BCHUNK : TOT_E;
    for (int base = lo; base < lo + BCHUNK; base += 256) {
        int i = base + tid;
        if (i < hi) {
            int s, d;
            if (i < N_EDGES) { s = ei[i]; d = ei[N_EDGES + i]; }
            else { s = d = i - N_EDGES; }
            pk[i - lo] = ((unsigned)d << 16) | (unsigned)s;
            atomicAdd(&hist[d >> 8], 1);
        }
    }
    __syncthreads();
    for (int t = tid; t < NP; t += 256) runb[t] = atomicAdd(&gcur[t], hist[t]);
    __syncthreads();
    for (int base = lo; base < lo + BCHUNK; base += 256) {
        int i = base + tid;
        if (i < hi) {
            unsigned v = pk[i - lo];
            int p = v >> 24;
            int slot = atomicAdd(&runb[p], 1);
            if (slot < BCAP) buckets[(size_t)p * BCAP + slot] = v;
        }
    }
}

// csr_kernel: one block per partition. Two-key counting sort: (dst-local, src-slice src>>13)
// -> 2048 bins, so each node's edge list is ordered by src slice. Combined with agg's
// stride-4 streams, all waves sweep src slices near-lockstep -> gathers become L2-resident.
__global__ __launch_bounds__(256) void csr_kernel(const int* __restrict__ gcur,
                                                  const unsigned int* __restrict__ buckets,
                                                  int* __restrict__ pbeg, int* __restrict__ pend,
                                                  unsigned short* __restrict__ srcs) {
    __shared__ unsigned int epk[BCAP];      // 24 KB
    __shared__ unsigned short sl[BCAP];     // 12 KB
    __shared__ int hist[2048];              // 8 KB (256 nodes x 8 src-slices)
    __shared__ int ps[256];
    int p = blockIdx.x, tid = threadIdx.x;
    int len = gcur[p];
    if (len > BCAP) len = BCAP;
    for (int j = tid; j < 2048; j += 256) hist[j] = 0;
    __syncthreads();
    for (int j = tid; j < len; j += 256) {
        unsigned v = buckets[(size_t)p * BCAP + j];
        epk[j] = v;
        int key = (((v >> 16) & 255) << 3) + ((v & 0xFFFF) >> 13);
        atomicAdd(&hist[key], 1);
    }
    __syncthreads();
    int binc[8];
    int v0 = 0;
#pragma unroll
    for (int k = 0; k < 8; ++k) { binc[k] = hist[tid * 8 + k]; v0 += binc[k]; }
    ps[tid] = v0;
    __syncthreads();
#pragma unroll
    for (int o = 1; o < 256; o <<= 1) {
        int u = (tid >= o) ? ps[tid - o] : 0;
        __syncthreads();
        ps[tid] += u;
        __syncthreads();
    }
    int lbeg = ps[tid] - v0;
    {
        int run = lbeg;
#pragma unroll
        for (int k = 0; k < 8; ++k) { int c = binc[k]; hist[tid * 8 + k] = run; run += c; }
    }
    int n = p * PS + tid;
    if (n < N_NODES) {
        pbeg[n] = p * BCAP + lbeg;
        pend[n] = p * BCAP + lbeg + v0;
    }
    __syncthreads();
    for (int j = tid; j < len; j += 256) {
        unsigned v = epk[j];
        int key = (((v >> 16) & 255) << 3) + ((v & 0xFFFF) >> 13);
        int slot = atomicAdd(&hist[key], 1);
        sl[slot] = (unsigned short)(v & 0xFFFF);
    }
    __syncthreads();
    for (int j = tid; j < len; j += 256) srcs[(size_t)p * BCAP + j] = sl[j];
}

// Mt[l][c][kc] = bf16(0.5*W[l][kc&127][(kc>>7)*128 + c])  (B^T layout, 128 cols x 256 k)
__global__ __launch_bounds__(256) void mt_kernel(const float* __restrict__ W, unsigned short* __restrict__ Mt) {
    int idx = blockIdx.x * 256 + threadIdx.x;  // 65536
    int l = idx >> 15, c = (idx >> 8) & 127, kc = idx & 255;
    int head = kc >> 7, k = kc & 127;
    Mt[idx] = f2bf(0.5f * W[(size_t)l * 32768 + (size_t)k * 256 + head * 128 + c]);
}

// x (fp32) -> xb (bf16) + layer-0 attention logits (32 threads per node, shuffle reduce).
__global__ __launch_bounds__(256) void convert_kernel(const float* __restrict__ x, unsigned short* __restrict__ xb,
                                                      const float* __restrict__ was, const float* __restrict__ wad,
                                                      float2* __restrict__ als, float2* __restrict__ ald) {
    int idx = blockIdx.x * 256 + threadIdx.x;
    int n = idx >> 5;
    int c4 = (idx & 31) * 4;
    float4 v = *(const float4*)(x + (size_t)n * 128 + c4);
    ushort4 o;
    o.x = f2bf(v.x); o.y = f2bf(v.y); o.z = f2bf(v.z); o.w = f2bf(v.w);
    *(ushort4*)(xb + (size_t)n * 128 + c4) = o;
    float4 ws0 = *(const float4*)(was + c4);
    float4 ws1 = *(const float4*)(was + 128 + c4);
    float4 wd0 = *(const float4*)(wad + c4);
    float4 wd1 = *(const float4*)(wad + 128 + c4);
    float s0 = v.x * ws0.x + v.y * ws0.y + v.z * ws0.z + v.w * ws0.w;
    float s1 = v.x * ws1.x + v.y * ws1.y + v.z * ws1.z + v.w * ws1.w;
    float d0 = v.x * wd0.x + v.y * wd0.y + v.z * wd0.z + v.w * wd0.w;
    float d1 = v.x * wd1.x + v.y * wd1.y + v.z * wd1.z + v.w * wd1.w;
#pragma unroll
    for (int o2 = 1; o2 < 32; o2 <<= 1) {
        s0 += __shfl_xor(s0, o2);
        s1 += __shfl_xor(s1, o2);
        d0 += __shfl_xor(d0, o2);
        d1 += __shfl_xor(d1, o2);
    }
    if ((idx & 31) == 0) {
        als[n] = make_float2(s0, s1);
        ald[n] = make_float2(d0, d1);
    }
}

// ---------------- per-layer kernels ----------------
// 16-lane group per node (4 consecutive nodes/wave); lane covers 8 bf16 cols.
// FOUR ILP streams, STRIDE-4 interleaved: with src-sorted lists the in-flight gathers
// are consecutive in src, and all waves sweep slices near-lockstep (L2-resident).
__global__ __launch_bounds__(256) void agg_kernel(const unsigned short* __restrict__ xb,
                                                  const float2* __restrict__ als, const float2* __restrict__ ald,
                                                  const int* __restrict__ pbeg, const int* __restrict__ pend,
                                                  const unsigned short* __restrict__ srcs,
                                                  unsigned short* __restrict__ y) {
    int tid = blockIdx.x * 256 + threadIdx.x;
    int n = tid >> 4;
    int gl = tid & 15;
    if (n >= N_NODES) return;
    int b = pbeg[n], e = pend[n];
    float2 ad = ald[n];
    int cb = gl * 8;   // col base

    float a0[8], a1[8];
#pragma unroll
    for (int j = 0; j < 8; ++j) { a0[j] = 0.f; a1[j] = 0.f; }
    float d0 = 0.f, d1 = 0.f;

    int len = e - b;
    int L = (len + 3) >> 2;
    for (int i = 0; i < L; ++i) {
        int e0 = i << 2;
        bool c0 = e0 < len, c1 = e0 + 1 < len, c2 = e0 + 2 < len, c3 = e0 + 3 < len;
        int i0 = b + (c0 ? e0 : 0);
        int i1 = b + (c1 ? e0 + 1 : 0);
        int i2 = b + (c2 ? e0 + 2 : 0);
        int i3 = b + (c3 ? e0 + 3 : 0);
        int s0 = srcs[i0], s1 = srcs[i1], s2 = srcs[i2], s3 = srcs[i3];
        float2 A0 = als[s0], A1 = als[s1], A2 = als[s2], A3 = als[s3];
        us8 v0 = *(const us8*)(xb + (size_t)s0 * 128 + cb);
        us8 v1 = *(const us8*)(xb + (size_t)s1 * 128 + cb);
        us8 v2 = *(const us8*)(xb + (size_t)s2 * 128 + cb);
        us8 v3 = *(const us8*)(xb + (size_t)s3 * 128 + cb);
        float w00 = c0 ? __expf(lrelu(A0.x + ad.x)) : 0.f;
        float w10 = c0 ? __expf(lrelu(A0.y + ad.y)) : 0.f;
        float w01 = c1 ? __expf(lrelu(A1.x + ad.x)) : 0.f;
        float w11 = c1 ? __expf(lrelu(A1.y + ad.y)) : 0.f;
        float w02 = c2 ? __expf(lrelu(A2.x + ad.x)) : 0.f;
        float w12 = c2 ? __expf(lrelu(A2.y + ad.y)) : 0.f;
        float w03 = c3 ? __expf(lrelu(A3.x + ad.x)) : 0.f;
        float w13 = c3 ? __expf(lrelu(A3.y + ad.y)) : 0.f;
        d0 += (w00 + w01) + (w02 + w03);
        d1 += (w10 + w11) + (w12 + w13);
#pragma unroll
        for (int j = 0; j < 8; ++j) {
            float f0 = bf2f(v0[j]);
            float f1 = bf2f(v1[j]);
            float f2 = bf2f(v2[j]);
            float f3 = bf2f(v3[j]);
            a0[j] += (w00 * f0 + w01 * f1) + (w02 * f2 + w03 * f3);
            a1[j] += (w10 * f0 + w11 * f1) + (w12 * f2 + w13 * f3);
        }
    }

    float i0v = 1.0f / d0, i1v = 1.0f / d1;
    us8 o0, o1;
#pragma unroll
    for (int j = 0; j < 8; ++j) {
        o0[j] = f2bf(a0[j] * i0v);
        o1[j] = f2bf(a1[j] * i1v);
    }
    unsigned short* yp = y + (size_t)n * 256 + cb;
    *(us8*)yp = o0;
    *(us8*)(yp + 128) = o1;
}

// pre = z @ M + bias : (N,256)bf16 @ (256,128) -> bf16 (N,128) + fused BN stats.
__global__ __launch_bounds__(256) void gemm2_kernel(const unsigned short* __restrict__ zb,
                                                    const unsigned short* __restrict__ Mt,
                                                    const float* __restrict__ bias_,
                                                    unsigned short* __restrict__ preb,
                                                    float* __restrict__ stats) {
    __shared__ unsigned short lw[128 * 128];  // 32KB
    __shared__ float redsum[4][128];
    __shared__ float redsq[4][128];
    int t = threadIdx.x;
    int w = t >> 6, l = t & 63;
    int r0 = blockIdx.x * 64 + w * 16;
    int lrow = l & 15;
    int lk = l >> 4;

    int arow = r0 + lrow;
    if (arow >= N_NODES) arow = N_NODES - 1;

    f32x4 acc[8];
#pragma unroll
    for (int i = 0; i < 8; ++i) acc[i] = (f32x4){0.f, 0.f, 0.f, 0.f};

    for (int kh = 0; kh < 2; ++kh) {
#pragma unroll
        for (int i = 0; i < 8; ++i) {
            int chunk = t + i * 256;            // 0..2047
            int row = chunk >> 4;               // col 0..127
            int kc8 = chunk & 15;
            uint4 v = *(const uint4*)(Mt + (size_t)row * 256 + kh * 128 + kc8 * 8);
            int b = row * 256 + ((kc8 * 16) ^ ((row & 7) << 4));
            *(uint4*)((char*)lw + b) = v;
        }
        __syncthreads();
        s16x8 a[4];
#pragma unroll
        for (int ka = 0; ka < 4; ++ka)
            a[ka] = *(const s16x8*)(zb + (size_t)arow * 256 + kh * 128 + ka * 32 + lk * 8);
#pragma unroll
        for (int ct = 0; ct < 8; ++ct) {
            int row = ct * 16 + lrow;
#pragma unroll
            for (int ka = 0; ka < 4; ++ka) {
                int kb = (ka * 64 + lk * 16) ^ ((row & 7) << 4);
                s16x8 bf = *(const s16x8*)((const char*)lw + row * 256 + kb);
                acc[ct] = __builtin_amdgcn_mfma_f32_16x16x32_bf16(a[ka], bf, acc[ct], 0, 0, 0);
            }
        }
        __syncthreads();   // all waves done reading lw before epilogue reuses it
    }

    // epilogue: per-wave LDS transpose -> bf16 stores + stats accumulation (no syncs)
    float* fl = (float*)lw;
    int wbase = w * 704;  // 4 rows x 176 words per wave (private region)
    int lr2 = l >> 4;
    int cb2 = (l & 15) * 8;
    float4 b0 = *(const float4*)(bias_ + cb2);
    float4 b1 = *(const float4*)(bias_ + cb2 + 4);
    float ssum[8], ssq[8];
#pragma unroll
    for (int j = 0; j < 8; ++j) { ssum[j] = 0.f; ssq[j] = 0.f; }
#pragma unroll
    for (int reg = 0; reg < 4; ++reg) {
#pragma unroll
        for (int ct = 0; ct < 8; ++ct)
            fl[wbase + lk * 176 + ct * 20 + lrow] = acc[ct][reg];
        int ra = wbase + lr2 * 176 + (cb2 >> 4) * 20 + (cb2 & 15);
        f32x4 v0 = *(const f32x4*)(fl + ra);
        f32x4 v1 = *(const f32x4*)(fl + ra + 4);
        int row = r0 + lr2 * 4 + reg;
        if (row < N_NODES) {
            float vals[8] = {v0[0] + b0.x, v0[1] + b0.y, v0[2] + b0.z, v0[3] + b0.w,
                             v1[0] + b1.x, v1[1] + b1.y, v1[2] + b1.z, v1[3] + b1.w};
            us8 ob;
#pragma unroll
            for (int j = 0; j < 8; ++j) {
                ob[j] = f2bf(vals[j]);
                ssum[j] += vals[j];
                ssq[j] += vals[j] * vals[j];
            }
            *(us8*)(preb + (size_t)row * 128 + cb2) = ob;
        }
    }
    // stats: reduce the 4 lanes sharing cb2 (xor 16, 32), stash per wave, reduce waves, atomics
#pragma unroll
    for (int j = 0; j < 8; ++j) {
        ssum[j] += __shfl_xor(ssum[j], 16);
        ssum[j] += __shfl_xor(ssum[j], 32);
        ssq[j] += __shfl_xor(ssq[j], 16);
        ssq[j] += __shfl_xor(ssq[j], 32);
    }
    if (l < 16) {
#pragma unroll
        for (int j = 0; j < 8; ++j) {
            redsum[w][cb2 + j] = ssum[j];
            redsq[w][cb2 + j] = ssq[j];
        }
    }
    __syncthreads();
    if (t < 128) {
        atomicAdd(&stats[t], redsum[0][t] + redsum[1][t] + redsum[2][t] + redsum[3][t]);
    } else if (t < 256) {
        int c = t - 128;
        atomicAdd(&stats[128 + c], redsq[0][c] + redsq[1][c] + redsq[2][c] + redsq[3][c]);
    }
}

// BN + ELU + residual from bf16 pre. Residual from fp32 (resf, layer 0) or bf16 (resb, layer 1).
// Layer 0 writes ONLY bf16 xb_out (+ next-layer logits); layer 1 writes only fp32 out.
__global__ __launch_bounds__(256) void final_kernel(const unsigned short* __restrict__ preb,
                                                    const float* __restrict__ resf,
                                                    const unsigned short* __restrict__ resb,
                                                    const float* __restrict__ gamma, const float* __restrict__ beta,
                                                    const float* __restrict__ stats, float* __restrict__ out,
                                                    unsigned short* __restrict__ xb_out,
                                                    const float* __restrict__ was_n, const float* __restrict__ wad_n,
                                                    float2* __restrict__ als_o, float2* __restrict__ ald_o) {
    const float invn = 1.0f / (float)N_NODES;
    int idx = blockIdx.x * 256 + threadIdx.x;
    int n = idx >> 4;
    int c8 = (idx & 15) * 8;
    us8 pv = *(const us8*)(preb + (size_t)n * 128 + c8);
    float rs[8];
    if (resf) {
        float4 r0 = *(const float4*)(resf + (size_t)n * 128 + c8);
        float4 r1 = *(const float4*)(resf + (size_t)n * 128 + c8 + 4);
        rs[0] = r0.x; rs[1] = r0.y; rs[2] = r0.z; rs[3] = r0.w;
        rs[4] = r1.x; rs[5] = r1.y; rs[6] = r1.z; rs[7] = r1.w;
    } else {
        us8 rv = *(const us8*)(resb + (size_t)n * 128 + c8);
#pragma unroll
        for (int j = 0; j < 8; ++j) rs[j] = bf2f(rv[j]);
    }
    float4 sm0 = *(const float4*)(stats + c8);
    float4 sm1 = *(const float4*)(stats + c8 + 4);
    float4 sq0 = *(const float4*)(stats + 128 + c8);
    float4 sq1 = *(const float4*)(stats + 128 + c8 + 4);
    float4 g0 = *(const float4*)(gamma + c8);
    float4 g1 = *(const float4*)(gamma + c8 + 4);
    float4 bt0 = *(const float4*)(beta + c8);
    float4 bt1 = *(const float4*)(beta + c8 + 4);
    float sm[8] = {sm0.x, sm0.y, sm0.z, sm0.w, sm1.x, sm1.y, sm1.z, sm1.w};
    float sq[8] = {sq0.x, sq0.y, sq0.z, sq0.w, sq1.x, sq1.y, sq1.z, sq1.w};
    float gg[8] = {g0.x, g0.y, g0.z, g0.w, g1.x, g1.y, g1.z, g1.w};
    float bb[8] = {bt0.x, bt0.y, bt0.z, bt0.w, bt1.x, bt1.y, bt1.z, bt1.w};
    float vals[8];
#pragma unroll
    for (int j = 0; j < 8; ++j) {
        float mean = sm[j] * invn;
        float var = sq[j] * invn - mean * mean;
        float is = rsqrtf(var + 1e-5f) * gg[j];
        float val = (bf2f(pv[j]) - mean) * is + bb[j];
        val = val > 0.f ? val : (__expf(val) - 1.0f);
        vals[j] = val + rs[j];
    }
    if (out) {
        float* op = out + (size_t)n * 128 + c8;
        *(float4*)op = make_float4(vals[0], vals[1], vals[2], vals[3]);
        *(float4*)(op + 4) = make_float4(vals[4], vals[5], vals[6], vals[7]);
    }
    if (xb_out) {
        us8 ob;
#pragma unroll
        for (int j = 0; j < 8; ++j) ob[j] = f2bf(vals[j]);
        *(us8*)(xb_out + (size_t)n * 128 + c8) = ob;
        // next-layer attention logits
        float s0 = 0.f, s1 = 0.f, d0 = 0.f, d1 = 0.f;
#pragma unroll
        for (int j = 0; j < 8; ++j) {
            int c = c8 + j;
            s0 += vals[j] * was_n[c];
            s1 += vals[j] * was_n[128 + c];
            d0 += vals[j] * wad_n[c];
            d1 += vals[j] * wad_n[128 + c];
        }
#pragma unroll
        for (int o = 1; o < 16; o <<= 1) {
            s0 += __shfl_xor(s0, o);
            s1 += __shfl_xor(s1, o);
            d0 += __shfl_xor(d0, o);
            d1 += __shfl_xor(d1, o);
        }
        if ((idx & 15) == 0) {
            als_o[n] = make_float2(s0, s1);
            ald_o[n] = make_float2(d0, d1);
        }
    }
}

extern "C" void kernel_launch(void* const* d_in, const int* in_sizes, int n_in,
                              void* d_out, int out_size, void* d_ws, size_t ws_size,
                              hipStream_t stream) {
    const float* x0   = (const float*)d_in[0];
    const int* ei     = (const int*)d_in[1];
    const float* W    = (const float*)d_in[2];
    const float* asrc = (const float*)d_in[3];
    const float* adst = (const float*)d_in[4];
    const float* bias = (const float*)d_in[5];
    const float* gam  = (const float*)d_in[6];
    const float* bet  = (const float*)d_in[7];
    float* out = (float*)d_out;

    char* ws = (char*)d_ws;
    size_t off = 0;
    auto alloc = [&](size_t bytes) -> void* {
        void* p = ws + off;
        off += (bytes + 255) & ~(size_t)255;
        return p;
    };
    int* gcur   = (int*)alloc((size_t)NP * 4);
    unsigned int* buckets = (unsigned int*)alloc((size_t)NP * BCAP * 4);
    unsigned short* srcs  = (unsigned short*)alloc((size_t)NP * BCAP * 2);
    int* pbeg   = (int*)alloc((size_t)N_NODES * 4);
    int* pend   = (int*)alloc((size_t)N_NODES * 4);
    unsigned short* xb = (unsigned short*)alloc((size_t)N_NODES * 128 * 2);   // bf16 layer input / L1 residual
    unsigned short* y  = (unsigned short*)alloc((size_t)N_NODES * 256 * 2);   // bf16 z = [y_h0|y_h1]
    unsigned short* preb = (unsigned short*)alloc((size_t)N_NODES * 128 * 2); // bf16 pre-BN
    unsigned short* Mt = (unsigned short*)alloc((size_t)2 * 128 * 256 * 2);   // bf16 M^T per layer
    float* was  = (float*)alloc(512 * 4);
    float* wad  = (float*)alloc(512 * 4);
    float* als  = (float*)alloc((size_t)N_NODES * 2 * 4);
    float* ald  = (float*)alloc((size_t)N_NODES * 2 * 4);
    float* stats = (float*)alloc(512 * 4);

    wa_kernel<<<2, 256, 0, stream>>>(W, asrc, adst, was, wad, gcur, stats);
    bucket_kernel<<<NBK, 256, 0, stream>>>(ei, gcur, buckets);
    csr_kernel<<<NP, 256, 0, stream>>>(gcur, buckets, pbeg, pend, srcs);
    mt_kernel<<<256, 256, 0, stream>>>(W, Mt);
    convert_kernel<<<(N_NODES * 32) / 256, 256, 0, stream>>>(x0, xb, was, wad, (float2*)als, (float2*)ald);

    for (int l = 0; l < 2; ++l) {
        agg_kernel<<<(N_NODES * 16 + 255) / 256, 256, 0, stream>>>(
            xb, (const float2*)als, (const float2*)ald, pbeg, pend, srcs, y);
        gemm2_kernel<<<(N_NODES + 63) / 64, 256, 0, stream>>>(
            y, Mt + (size_t)l * 32768, bias + l * 128, preb, stats + l * 256);
        final_kernel<<<(N_NODES * 16) / 256, 256, 0, stream>>>(
            preb,
            l == 0 ? x0 : (const float*)nullptr,
            l == 0 ? (const unsigned short*)nullptr : xb,
            gam + l * 128, bet + l * 128, stats + l * 256,
            l == 0 ? (float*)nullptr : out,
            l == 0 ? xb : (unsigned short*)nullptr,
            was + 256, wad + 256,
            (float2*)als, (float2*)ald);
    }
}